// Round 10
// baseline (576.207 us; speedup 1.0000x reference)
//
#include <hip/hip_runtime.h>

#define N_NODES 50000
#define N_EDGES 200000
#define DE 32
#define N_FRAG 10000
#define N_GRAPH 2000
#define BN_SLOTS 32
#define KSTR 296   // LDS k-stride (shorts) for 32-row A/h1 planes

typedef __attribute__((ext_vector_type(8))) short short8;
typedef __attribute__((ext_vector_type(4))) short s16x4;
typedef __attribute__((ext_vector_type(4))) float f32x4;

__device__ __forceinline__ unsigned short f2bf(float f) {
    unsigned u = __float_as_uint(f);
    u += 0x7FFF + ((u >> 16) & 1);      // RNE (no NaN inputs here)
    return (unsigned short)(u >> 16);
}

// split x = hi + lo (hi=bf16(x), lo=bf16(x-hi)); x-hi exact in fp32
__device__ __forceinline__ void split2(float f, unsigned short& h, unsigned short& l) {
    h = f2bf(f);
    float fh = __uint_as_float((unsigned)h << 16);
    l = f2bf(f - fh);
}

// ---------------------------------------------------------------------------
// CSR build: in-degree count, hierarchical scan, fill
__global__ __launch_bounds__(256)
void count_deg_kernel(const int* __restrict__ ei, int* __restrict__ deg) {
    int e = blockIdx.x * 256 + threadIdx.x;
    if (e < N_EDGES) atomicAdd(&deg[ei[N_EDGES + e]], 1);
}

__global__ __launch_bounds__(256)
void block_sum_kernel(const int* __restrict__ deg, int* __restrict__ bsum) {
    int i = blockIdx.x * 256 + threadIdx.x;
    int v = (i < N_NODES) ? deg[i] : 0;
#pragma unroll
    for (int o = 1; o < 64; o <<= 1) v += __shfl_xor(v, o);
    __shared__ int wsum[4];
    if ((threadIdx.x & 63) == 0) wsum[threadIdx.x >> 6] = v;
    __syncthreads();
    if (threadIdx.x == 0) bsum[blockIdx.x] = wsum[0] + wsum[1] + wsum[2] + wsum[3];
}

__global__ __launch_bounds__(256)
void top_scan_kernel(int* __restrict__ bsum, int nb) {
    __shared__ int s[256];
    int t = threadIdx.x;
    s[t] = (t < nb) ? bsum[t] : 0;
    __syncthreads();
    for (int o = 1; o < 256; o <<= 1) {
        int v = s[t];
        int a = (t >= o) ? s[t - o] : 0;
        __syncthreads();
        s[t] = v + a;
        __syncthreads();
    }
    if (t < nb) bsum[t] = (t > 0) ? s[t - 1] : 0;
}

__global__ __launch_bounds__(256)
void final_scan_kernel(const int* __restrict__ deg, const int* __restrict__ bsum,
                       int* __restrict__ ptr) {
    __shared__ int s[256];
    int i = blockIdx.x * 256 + threadIdx.x;
    int t = threadIdx.x;
    int v = (i < N_NODES) ? deg[i] : 0;
    s[t] = v;
    __syncthreads();
    for (int o = 1; o < 256; o <<= 1) {
        int x = s[t];
        int a = (t >= o) ? s[t - o] : 0;
        __syncthreads();
        s[t] = x + a;
        __syncthreads();
    }
    int incl = s[t];
    int base = bsum[blockIdx.x];
    if (i < N_NODES) ptr[i] = base + incl - v;
    if (i == N_NODES - 1) ptr[N_NODES] = base + incl;
}

__global__ __launch_bounds__(256)
void fill_csr_kernel(const int* __restrict__ ei, const int* __restrict__ row_ptr,
                     int* __restrict__ fill, int* __restrict__ csr_src,
                     int* __restrict__ csr_eid) {
    int e = blockIdx.x * 256 + threadIdx.x;
    if (e >= N_EDGES) return;
    int dst = ei[N_EDGES + e];
    int pos = row_ptr[dst] + atomicAdd(&fill[dst], 1);
    csr_src[pos] = ei[e];
    csr_eid[pos] = e;
}

__global__ __launch_bounds__(256)
void segptr_kernel(const int* __restrict__ batch, int nseg, int* __restrict__ ptr) {
    int s = blockIdx.x * 256 + threadIdx.x;
    if (s > nseg) return;
    int lo = 0, hi = N_NODES;
    while (lo < hi) {
        int mid = (lo + hi) >> 1;
        if (batch[mid] < s) lo = mid + 1; else hi = mid;
    }
    ptr[s] = lo;
}

// ---------------------------------------------------------------------------
// W [K][256] fp32 -> fragment-swizzled BShi/BSlo:
// BS[kt][cg][lane][j] = split(W[kt*32 + (lane>>4)*8 + j][cg*16 + (lane&15)])
__global__ __launch_bounds__(256)
void bs_kernel(const float* __restrict__ W, unsigned short* __restrict__ BShi,
               unsigned short* __restrict__ BSlo, int K) {
    int id = blockIdx.x * 256 + threadIdx.x;
    if (id >= K * 256) return;
    int j  = id & 7;
    int l  = (id >> 3) & 63;
    int cg = (id >> 9) & 15;
    int kt = id >> 13;
    int col = cg * 16 + (l & 15);
    int k   = kt * 32 + (l >> 4) * 8 + j;
    unsigned short h, lo;
    split2(W[(size_t)k * 256 + col], h, lo);
    BShi[id] = h;
    BSlo[id] = lo;
}

// ---------------------------------------------------------------------------
// agg_e[n] = sum over incoming edges of relu(edge_attr[e])  [N,32]
__global__ __launch_bounds__(256)
void edge_gather_kernel(const float* __restrict__ ea, const int* __restrict__ row_ptr,
                        const int* __restrict__ csr_eid, float* __restrict__ agg_e) {
    int t = threadIdx.x;
    int g = t >> 3;
    int j = t & 7;
    int n = blockIdx.x * 32 + g;
    if (n >= N_NODES) return;
    int col = j << 2;
    float4 acc = {0.f, 0.f, 0.f, 0.f};
    int beg = row_ptr[n], end = row_ptr[n + 1];
    for (int e = beg; e < end; ++e) {
        int eid = csr_eid[e];
        float4 v = *(const float4*)(ea + (size_t)eid * DE + col);
        acc.x += fmaxf(v.x, 0.f);
        acc.y += fmaxf(v.y, 0.f);
        acc.z += fmaxf(v.z, 0.f);
        acc.w += fmaxf(v.w, 0.f);
    }
    *(float4*)(agg_e + (size_t)n * DE + col) = acc;
}

// ---------------------------------------------------------------------------
// Fully fused GINE layer: gather(BN-on-load) -> GEMM1 -> ReLU -> GEMM2 -> ReLU
// -> store + BN stats. agg and h1 never touch global memory.
// Block: 256 thr (4 waves), 32 rows. LDS A/h1 planes reused (union).
template <bool BNIN, int DIN>
__global__ __launch_bounds__(256, 4)
void fused_layer_kernel(const float* __restrict__ xin, const int* __restrict__ row_ptr,
                        const int* __restrict__ csr_src, const float* __restrict__ agg_e,
                        const float* __restrict__ bnsc, const float* __restrict__ bnsh,
                        const unsigned short* __restrict__ B1hi, const unsigned short* __restrict__ B1lo,
                        const float* __restrict__ bias1,
                        const unsigned short* __restrict__ B2hi, const unsigned short* __restrict__ B2lo,
                        const float* __restrict__ bias2,
                        float* __restrict__ xout, float* __restrict__ bnslot) {
    constexpr int FIN = DIN + 32;
    constexpr int NKT1 = FIN >> 5;     // 5 (DIN=128) or 9 (DIN=256)
    constexpr int ND = DIN >> 5;       // float4s per gather thread: 4 or 8
    __shared__ __align__(16) unsigned short sAhi[32 * KSTR];  // A tile, then h1-hi
    __shared__ __align__(16) unsigned short sAlo[32 * KSTR];  // A tile, then h1-lo
    __shared__ float sSc[256], sSh[256];
    const int t = threadIdx.x;
    const int l = t & 63;
    const int w = t >> 6;
    const int lr = l & 15;
    const int lq = l >> 4;
    const int row0 = blockIdx.x << 5;   // 32 rows/block
    const int cb = w << 6;

    if (BNIN && t < DIN) { sSc[t] = bnsc[t]; sSh[t] = bnsh[t]; }
    if (BNIN) __syncthreads();

    // ---- gather phase: agg rows in registers -> LDS (bf16 hi/lo) ----
    {
        const int r = t >> 3, j = t & 7;    // 8 threads per row
        const int n = row0 + r;
        f32x4 acc[ND];
#pragma unroll
        for (int i = 0; i < ND; ++i) acc[i] = (f32x4){0.f, 0.f, 0.f, 0.f};
        float4 accE = {0.f, 0.f, 0.f, 0.f};
        if (n < N_NODES) {
            const float* xp = xin + (size_t)n * DIN;
#pragma unroll
            for (int i = 0; i < ND; ++i) {        // self term: BN, no relu
                int c = (j << 2) + (i << 5);
                float4 v = *(const float4*)(xp + c);
                if (BNIN) {
                    float4 sc = *(const float4*)&sSc[c];
                    float4 sh = *(const float4*)&sSh[c];
                    v.x = fmaf(v.x, sc.x, sh.x); v.y = fmaf(v.y, sc.y, sh.y);
                    v.z = fmaf(v.z, sc.z, sh.z); v.w = fmaf(v.w, sc.w, sh.w);
                }
                acc[i] = (f32x4){v.x, v.y, v.z, v.w};
            }
            int beg = row_ptr[n], end = row_ptr[n + 1];
            for (int e = beg; e < end; ++e) {
                const float* sp = xin + (size_t)csr_src[e] * DIN;
#pragma unroll
                for (int i = 0; i < ND; ++i) {    // neighbors: BN then relu
                    int c = (j << 2) + (i << 5);
                    float4 v = *(const float4*)(sp + c);
                    if (BNIN) {
                        float4 sc = *(const float4*)&sSc[c];
                        float4 sh = *(const float4*)&sSh[c];
                        v.x = fmaf(v.x, sc.x, sh.x); v.y = fmaf(v.y, sc.y, sh.y);
                        v.z = fmaf(v.z, sc.z, sh.z); v.w = fmaf(v.w, sc.w, sh.w);
                    }
                    acc[i].x += fmaxf(v.x, 0.f);
                    acc[i].y += fmaxf(v.y, 0.f);
                    acc[i].z += fmaxf(v.z, 0.f);
                    acc[i].w += fmaxf(v.w, 0.f);
                }
            }
            accE = *(const float4*)(agg_e + (size_t)n * DE + (j << 2));
        }
        // convert + store A tile
#pragma unroll
        for (int i = 0; i < ND; ++i) {
            int c = (j << 2) + (i << 5);
            s16x4 hv, lv; unsigned short h, lo_;
            split2(acc[i].x, h, lo_); hv[0] = (short)h; lv[0] = (short)lo_;
            split2(acc[i].y, h, lo_); hv[1] = (short)h; lv[1] = (short)lo_;
            split2(acc[i].z, h, lo_); hv[2] = (short)h; lv[2] = (short)lo_;
            split2(acc[i].w, h, lo_); hv[3] = (short)h; lv[3] = (short)lo_;
            *(s16x4*)&sAhi[r * KSTR + c] = hv;
            *(s16x4*)&sAlo[r * KSTR + c] = lv;
        }
        {
            int c = DIN + (j << 2);
            s16x4 hv, lv; unsigned short h, lo_;
            split2(accE.x, h, lo_); hv[0] = (short)h; lv[0] = (short)lo_;
            split2(accE.y, h, lo_); hv[1] = (short)h; lv[1] = (short)lo_;
            split2(accE.z, h, lo_); hv[2] = (short)h; lv[2] = (short)lo_;
            split2(accE.w, h, lo_); hv[3] = (short)h; lv[3] = (short)lo_;
            *(s16x4*)&sAhi[r * KSTR + c] = hv;
            *(s16x4*)&sAlo[r * KSTR + c] = lv;
        }
    }
    __syncthreads();

    // ---- phase 1: agg @ W1 (A from LDS, barrier-free K-loop) ----
    f32x4 acc1[2][4];
#pragma unroll
    for (int mt = 0; mt < 2; ++mt)
#pragma unroll
        for (int nt = 0; nt < 4; ++nt) acc1[mt][nt] = (f32x4){0.f, 0.f, 0.f, 0.f};
#pragma unroll
    for (int kt = 0; kt < NKT1; ++kt) {
        short8 afh[2], afl[2], bfh[4], bfl[4];
#pragma unroll
        for (int mt = 0; mt < 2; ++mt) {
            int so = (mt * 16 + lr) * KSTR + (kt << 5) + (lq << 3);
            afh[mt] = *(const short8*)&sAhi[so];
            afl[mt] = *(const short8*)&sAlo[so];
        }
        const size_t bb = ((size_t)(kt * 16 + (w << 2))) * 512 + (l << 3);
#pragma unroll
        for (int nt = 0; nt < 4; ++nt) {
            bfh[nt] = *(const short8*)(B1hi + bb + nt * 512);
            bfl[nt] = *(const short8*)(B1lo + bb + nt * 512);
        }
#pragma unroll
        for (int mt = 0; mt < 2; ++mt)
#pragma unroll
            for (int nt = 0; nt < 4; ++nt) {
                acc1[mt][nt] = __builtin_amdgcn_mfma_f32_16x16x32_bf16(afl[mt], bfh[nt], acc1[mt][nt], 0, 0, 0);
                acc1[mt][nt] = __builtin_amdgcn_mfma_f32_16x16x32_bf16(afh[mt], bfl[nt], acc1[mt][nt], 0, 0, 0);
                acc1[mt][nt] = __builtin_amdgcn_mfma_f32_16x16x32_bf16(afh[mt], bfh[nt], acc1[mt][nt], 0, 0, 0);
            }
    }
    __syncthreads();   // A tile dead; reuse planes for h1

    // ---- epilogue 1: relu(h1) -> LDS hi/lo ----
#pragma unroll
    for (int nt = 0; nt < 4; ++nt) {
        int col = cb + nt * 16 + lr;
        float bv = bias1[col];
#pragma unroll
        for (int mt = 0; mt < 2; ++mt)
#pragma unroll
            for (int i = 0; i < 4; ++i) {
                int rr = mt * 16 + lq * 4 + i;
                float o = fmaxf(acc1[mt][nt][i] + bv, 0.f);
                unsigned short h, lo_;
                split2(o, h, lo_);
                sAhi[rr * KSTR + col] = h;
                sAlo[rr * KSTR + col] = lo_;
            }
    }
    __syncthreads();

    // ---- phase 2: h1 @ W2 (barrier-free) ----
    f32x4 acc2[2][4];
#pragma unroll
    for (int mt = 0; mt < 2; ++mt)
#pragma unroll
        for (int nt = 0; nt < 4; ++nt) acc2[mt][nt] = (f32x4){0.f, 0.f, 0.f, 0.f};
#pragma unroll
    for (int kt = 0; kt < 8; ++kt) {
        short8 afh[2], afl[2], bfh[4], bfl[4];
#pragma unroll
        for (int mt = 0; mt < 2; ++mt) {
            int so = (mt * 16 + lr) * KSTR + (kt << 5) + (lq << 3);
            afh[mt] = *(const short8*)&sAhi[so];
            afl[mt] = *(const short8*)&sAlo[so];
        }
        const size_t bb = ((size_t)(kt * 16 + (w << 2))) * 512 + (l << 3);
#pragma unroll
        for (int nt = 0; nt < 4; ++nt) {
            bfh[nt] = *(const short8*)(B2hi + bb + nt * 512);
            bfl[nt] = *(const short8*)(B2lo + bb + nt * 512);
        }
#pragma unroll
        for (int mt = 0; mt < 2; ++mt)
#pragma unroll
            for (int nt = 0; nt < 4; ++nt) {
                acc2[mt][nt] = __builtin_amdgcn_mfma_f32_16x16x32_bf16(afl[mt], bfh[nt], acc2[mt][nt], 0, 0, 0);
                acc2[mt][nt] = __builtin_amdgcn_mfma_f32_16x16x32_bf16(afh[mt], bfl[nt], acc2[mt][nt], 0, 0, 0);
                acc2[mt][nt] = __builtin_amdgcn_mfma_f32_16x16x32_bf16(afh[mt], bfh[nt], acc2[mt][nt], 0, 0, 0);
            }
    }

    // ---- epilogue 2: bias + relu + store + BN stats ----
    float* slot = bnslot + (size_t)(blockIdx.x & (BN_SLOTS - 1)) * 512;
#pragma unroll
    for (int nt = 0; nt < 4; ++nt) {
        int col = cb + nt * 16 + lr;
        float bv = bias2[col];
        float s = 0.f, qq = 0.f;
#pragma unroll
        for (int mt = 0; mt < 2; ++mt)
#pragma unroll
            for (int i = 0; i < 4; ++i) {
                int row = row0 + mt * 16 + lq * 4 + i;
                if (row < N_NODES) {
                    float o = fmaxf(acc2[mt][nt][i] + bv, 0.f);
                    xout[(size_t)row * 256 + col] = o;
                    s += o; qq += o * o;
                }
            }
        s += __shfl_xor(s, 16); s += __shfl_xor(s, 32);
        qq += __shfl_xor(qq, 16); qq += __shfl_xor(qq, 32);
        if (lq == 0) {
            atomicAdd(&slot[col], s);
            atomicAdd(&slot[256 + col], qq);
        }
    }
}

// reduce BN_SLOTS slots -> scale/shift
__global__ void bn_finalize_kernel(const float* __restrict__ slots,
                                   const float* __restrict__ g, const float* __restrict__ beta,
                                   float* __restrict__ scale, float* __restrict__ shift) {
    int c = threadIdx.x;
    float s = 0.f, q = 0.f;
    for (int k = 0; k < BN_SLOTS; ++k) {
        s += slots[(size_t)k * 512 + c];
        q += slots[(size_t)k * 512 + 256 + c];
    }
    float mu = s * (1.0f / N_NODES);
    float var = q * (1.0f / N_NODES) - mu * mu;
    float rstd = rsqrtf(var + 1e-5f);
    float sc = g[c] * rstd;
    scale[c] = sc;
    shift[c] = beta[c] - mu * sc;
}

// segmented sqrt-pool with BN applied at load; no atomics
__global__ __launch_bounds__(256)
void pool_seg_kernel(const float* __restrict__ h, const int* __restrict__ ptr,
                     const float* __restrict__ bnsc, const float* __restrict__ bnsh,
                     float* __restrict__ out, int nseg) {
    int t = threadIdx.x;
    int g = t >> 6;
    int j = t & 63;
    int s = blockIdx.x * 4 + g;
    if (s >= nseg) return;
    int beg = ptr[s], end = ptr[s + 1];
    int col = j << 2;
    float4 sc = *(const float4*)(bnsc + col);
    float4 sh = *(const float4*)(bnsh + col);
    float4 acc = {0.f, 0.f, 0.f, 0.f};
    for (int i = beg; i < end; ++i) {
        float4 v = *(const float4*)(h + (size_t)i * 256 + col);
        acc.x += fmaf(v.x, sc.x, sh.x);
        acc.y += fmaf(v.y, sc.y, sh.y);
        acc.z += fmaf(v.z, sc.z, sh.z);
        acc.w += fmaf(v.w, sc.w, sh.w);
    }
    float w = rsqrtf(fmaxf((float)(end - beg), 1.0f));
    float4 o = {acc.x * w, acc.y * w, acc.z * w, acc.w * w};
    *(float4*)(out + (size_t)s * 256 + col) = o;
}

// ---------------------------------------------------------------------------
extern "C" void kernel_launch(void* const* d_in, const int* in_sizes, int n_in,
                              void* d_out, int out_size, void* d_ws, size_t ws_size,
                              hipStream_t stream) {
    const float* x  = (const float*)d_in[0];
    const float* ea = (const float*)d_in[1];
    const int*   ei = (const int*)d_in[2];
    const int*   fb = (const int*)d_in[3];
    const int*   gb = (const int*)d_in[4];
    const float* W1[3]   = {(const float*)d_in[5],  (const float*)d_in[11], (const float*)d_in[17]};
    const float* B1[3]   = {(const float*)d_in[6],  (const float*)d_in[12], (const float*)d_in[18]};
    const float* W2[3]   = {(const float*)d_in[7],  (const float*)d_in[13], (const float*)d_in[19]};
    const float* B2[3]   = {(const float*)d_in[8],  (const float*)d_in[14], (const float*)d_in[20]};
    const float* G[3]    = {(const float*)d_in[9],  (const float*)d_in[15], (const float*)d_in[21]};
    const float* BETA[3] = {(const float*)d_in[10], (const float*)d_in[16], (const float*)d_in[22]};

    const int FIN[3] = {160, 288, 288};
    const int NBLK = (N_NODES + 255) / 256;      // scan blocks

    float* ws = (float*)d_ws;
    size_t off = 0;
    float* bufA  = ws + off; off += (size_t)N_NODES * 256;
    float* bufB  = ws + off; off += (size_t)N_NODES * 256;
    float* agg_e = ws + off; off += (size_t)N_NODES * DE;
    float* bnss  = ws + off; off += 3 * 512;                 // per layer: scale(256)|shift(256)
    float* bnslots = ws + off; off += (size_t)3 * BN_SLOTS * 512;
    unsigned short* w1hi[3]; unsigned short* w1lo[3];
    unsigned short* w2hi[3]; unsigned short* w2lo[3];
    {
        unsigned short* sw = (unsigned short*)(ws + off);
        unsigned short* sw0 = sw;
        for (int l = 0; l < 3; ++l) {
            w1hi[l] = sw; sw += 256 * FIN[l];
            w1lo[l] = sw; sw += 256 * FIN[l];
        }
        for (int l = 0; l < 3; ++l) {
            w2hi[l] = sw; sw += 256 * 256;
            w2lo[l] = sw; sw += 256 * 256;
        }
        off += (size_t)(sw - sw0 + 1) / 2;
    }
    int* iw      = (int*)(ws + off);
    int* row_ptr = iw;                     iw += N_NODES + 1;
    int* deg     = iw;                     iw += N_NODES;
    int* fill    = iw;                     iw += N_NODES;
    int* csr_src = iw;                     iw += N_EDGES;
    int* csr_eid = iw;                     iw += N_EDGES;
    int* frag_ptr = iw;                    iw += N_FRAG + 1;
    int* graph_ptr = iw;                   iw += N_GRAPH + 1;
    int* bsum    = iw;                     iw += NBLK;

    hipMemsetAsync(deg, 0, 2 * N_NODES * sizeof(int), stream);
    hipMemsetAsync(bnslots, 0, (size_t)3 * BN_SLOTS * 512 * sizeof(float), stream);

    // weight fragment-swizzle + bf16 hi/lo split (once per layer)
    for (int l = 0; l < 3; ++l) {
        bs_kernel<<<(FIN[l] * 256 + 255) / 256, 256, 0, stream>>>(W1[l], w1hi[l], w1lo[l], FIN[l]);
        bs_kernel<<<(256 * 256 + 255) / 256, 256, 0, stream>>>(W2[l], w2hi[l], w2lo[l], 256);
    }

    // CSR build (hierarchical scan)
    count_deg_kernel<<<(N_EDGES + 255) / 256, 256, 0, stream>>>(ei, deg);
    block_sum_kernel<<<NBLK, 256, 0, stream>>>(deg, bsum);
    top_scan_kernel<<<1, 256, 0, stream>>>(bsum, NBLK);
    final_scan_kernel<<<NBLK, 256, 0, stream>>>(deg, bsum, row_ptr);
    fill_csr_kernel<<<(N_EDGES + 255) / 256, 256, 0, stream>>>(ei, row_ptr, fill, csr_src, csr_eid);

    segptr_kernel<<<(N_FRAG + 1 + 255) / 256, 256, 0, stream>>>(fb, N_FRAG, frag_ptr);
    segptr_kernel<<<(N_GRAPH + 1 + 255) / 256, 256, 0, stream>>>(gb, N_GRAPH, graph_ptr);

    edge_gather_kernel<<<(N_NODES + 31) / 32, 256, 0, stream>>>(ea, row_ptr, csr_eid, agg_e);

    const int nblk = (N_NODES + 31) / 32;    // 1563 blocks, 32 rows each

    // layer 0: x -> bufA
    fused_layer_kernel<false, 128><<<nblk, 256, 0, stream>>>(
        x, row_ptr, csr_src, agg_e, nullptr, nullptr,
        w1hi[0], w1lo[0], B1[0], w2hi[0], w2lo[0], B2[0], bufA, bnslots);
    bn_finalize_kernel<<<1, 256, 0, stream>>>(bnslots, G[0], BETA[0], bnss, bnss + 256);

    // layer 1: bufA -> bufB (BN of layer 0 applied on load)
    fused_layer_kernel<true, 256><<<nblk, 256, 0, stream>>>(
        bufA, row_ptr, csr_src, agg_e, bnss, bnss + 256,
        w1hi[1], w1lo[1], B1[1], w2hi[1], w2lo[1], B2[1], bufB,
        bnslots + (size_t)BN_SLOTS * 512);
    bn_finalize_kernel<<<1, 256, 0, stream>>>(bnslots + (size_t)BN_SLOTS * 512,
                                              G[1], BETA[1], bnss + 512, bnss + 768);

    // layer 2: bufB -> bufA
    fused_layer_kernel<true, 256><<<nblk, 256, 0, stream>>>(
        bufB, row_ptr, csr_src, agg_e, bnss + 512, bnss + 768,
        w1hi[2], w1lo[2], B1[2], w2hi[2], w2lo[2], B2[2], bufA,
        bnslots + (size_t)2 * BN_SLOTS * 512);
    bn_finalize_kernel<<<1, 256, 0, stream>>>(bnslots + (size_t)2 * BN_SLOTS * 512,
                                              G[2], BETA[2], bnss + 1024, bnss + 1280);

    const float* fsc = bnss + 1024;   // layer-2 BN scale/shift
    const float* fsh = bnss + 1280;
    pool_seg_kernel<<<(N_FRAG + 3) / 4, 256, 0, stream>>>(bufA, frag_ptr, fsc, fsh,
                                                          (float*)d_out, N_FRAG);
    pool_seg_kernel<<<(N_GRAPH + 3) / 4, 256, 0, stream>>>(bufA, graph_ptr, fsc, fsh,
                                                           (float*)d_out + (size_t)N_FRAG * 256, N_GRAPH);
}

// Round 11
// 479.153 us; speedup vs baseline: 1.2026x; 1.2026x over previous
//
#include <hip/hip_runtime.h>

#define N_NODES 50000
#define N_EDGES 200000
#define DE 32
#define N_FRAG 10000
#define N_GRAPH 2000
#define BN_SLOTS 32
#define KSTR 296   // LDS stride (fp16 elems) for the 32-row A/h1 plane

typedef _Float16 f16x8 __attribute__((ext_vector_type(8)));
typedef _Float16 f16x4 __attribute__((ext_vector_type(4)));
typedef __attribute__((ext_vector_type(4))) float f32x4;

// ---------------------------------------------------------------------------
// CSR build: in-degree count, hierarchical scan, fill
__global__ __launch_bounds__(256)
void count_deg_kernel(const int* __restrict__ ei, int* __restrict__ deg) {
    int e = blockIdx.x * 256 + threadIdx.x;
    if (e < N_EDGES) atomicAdd(&deg[ei[N_EDGES + e]], 1);
}

__global__ __launch_bounds__(256)
void block_sum_kernel(const int* __restrict__ deg, int* __restrict__ bsum) {
    int i = blockIdx.x * 256 + threadIdx.x;
    int v = (i < N_NODES) ? deg[i] : 0;
#pragma unroll
    for (int o = 1; o < 64; o <<= 1) v += __shfl_xor(v, o);
    __shared__ int wsum[4];
    if ((threadIdx.x & 63) == 0) wsum[threadIdx.x >> 6] = v;
    __syncthreads();
    if (threadIdx.x == 0) bsum[blockIdx.x] = wsum[0] + wsum[1] + wsum[2] + wsum[3];
}

__global__ __launch_bounds__(256)
void top_scan_kernel(int* __restrict__ bsum, int nb) {
    __shared__ int s[256];
    int t = threadIdx.x;
    s[t] = (t < nb) ? bsum[t] : 0;
    __syncthreads();
    for (int o = 1; o < 256; o <<= 1) {
        int v = s[t];
        int a = (t >= o) ? s[t - o] : 0;
        __syncthreads();
        s[t] = v + a;
        __syncthreads();
    }
    if (t < nb) bsum[t] = (t > 0) ? s[t - 1] : 0;
}

__global__ __launch_bounds__(256)
void final_scan_kernel(const int* __restrict__ deg, const int* __restrict__ bsum,
                       int* __restrict__ ptr) {
    __shared__ int s[256];
    int i = blockIdx.x * 256 + threadIdx.x;
    int t = threadIdx.x;
    int v = (i < N_NODES) ? deg[i] : 0;
    s[t] = v;
    __syncthreads();
    for (int o = 1; o < 256; o <<= 1) {
        int x = s[t];
        int a = (t >= o) ? s[t - o] : 0;
        __syncthreads();
        s[t] = x + a;
        __syncthreads();
    }
    int incl = s[t];
    int base = bsum[blockIdx.x];
    if (i < N_NODES) ptr[i] = base + incl - v;
    if (i == N_NODES - 1) ptr[N_NODES] = base + incl;
}

__global__ __launch_bounds__(256)
void fill_csr_kernel(const int* __restrict__ ei, const int* __restrict__ row_ptr,
                     int* __restrict__ fill, int* __restrict__ csr_src,
                     int* __restrict__ csr_eid) {
    int e = blockIdx.x * 256 + threadIdx.x;
    if (e >= N_EDGES) return;
    int dst = ei[N_EDGES + e];
    int pos = row_ptr[dst] + atomicAdd(&fill[dst], 1);
    csr_src[pos] = ei[e];
    csr_eid[pos] = e;
}

__global__ __launch_bounds__(256)
void segptr_kernel(const int* __restrict__ batch, int nseg, int* __restrict__ ptr) {
    int s = blockIdx.x * 256 + threadIdx.x;
    if (s > nseg) return;
    int lo = 0, hi = N_NODES;
    while (lo < hi) {
        int mid = (lo + hi) >> 1;
        if (batch[mid] < s) lo = mid + 1; else hi = mid;
    }
    ptr[s] = lo;
}

// ---------------------------------------------------------------------------
// W [K][256] fp32 -> fragment-swizzled fp16 BS:
// BS[kt][cg][lane][j] = fp16(W[kt*32 + (lane>>4)*8 + j][cg*16 + (lane&15)])
__global__ __launch_bounds__(256)
void bs16_kernel(const float* __restrict__ W, _Float16* __restrict__ BS, int K) {
    int id = blockIdx.x * 256 + threadIdx.x;
    if (id >= K * 256) return;
    int j  = id & 7;
    int l  = (id >> 3) & 63;
    int cg = (id >> 9) & 15;
    int kt = id >> 13;
    int col = cg * 16 + (l & 15);
    int k   = kt * 32 + (l >> 4) * 8 + j;
    BS[id] = (_Float16)W[(size_t)k * 256 + col];
}

// ---------------------------------------------------------------------------
// agg_e[n] = sum over incoming edges of relu(edge_attr[e])  [N,32]
__global__ __launch_bounds__(256)
void edge_gather_kernel(const float* __restrict__ ea, const int* __restrict__ row_ptr,
                        const int* __restrict__ csr_eid, float* __restrict__ agg_e) {
    int t = threadIdx.x;
    int g = t >> 3;
    int j = t & 7;
    int n = blockIdx.x * 32 + g;
    if (n >= N_NODES) return;
    int col = j << 2;
    float4 acc = {0.f, 0.f, 0.f, 0.f};
    int beg = row_ptr[n], end = row_ptr[n + 1];
    for (int e = beg; e < end; ++e) {
        int eid = csr_eid[e];
        float4 v = *(const float4*)(ea + (size_t)eid * DE + col);
        acc.x += fmaxf(v.x, 0.f);
        acc.y += fmaxf(v.y, 0.f);
        acc.z += fmaxf(v.z, 0.f);
        acc.w += fmaxf(v.w, 0.f);
    }
    *(float4*)(agg_e + (size_t)n * DE + col) = acc;
}

// agg[n][0:din] = xin[n] + sum relu(xin[src]);  agg[n][din:fin] = agg_e[n]
// If BNIN: xin is pre-BN h, apply x = scale*h + shift at load (per-column).
template <bool BNIN>
__global__ __launch_bounds__(256)
void gather_agg_kernel(const float* __restrict__ x, const int* __restrict__ row_ptr,
                       const int* __restrict__ csr_src, const float* __restrict__ agg_e,
                       float* __restrict__ agg, const float* __restrict__ bnsc,
                       const float* __restrict__ bnsh, int din, int fin, int gsize_log2) {
    int t = threadIdx.x;
    int g = t >> gsize_log2;
    int j = t & ((1 << gsize_log2) - 1);
    int n = blockIdx.x * (256 >> gsize_log2) + g;
    if (n >= N_NODES) return;
    int col = j << 2;
    float4 sc, sh;
    if (BNIN) {
        sc = *(const float4*)(bnsc + col);
        sh = *(const float4*)(bnsh + col);
    }
    float4 acc = *(const float4*)(x + (size_t)n * din + col);  // self term
    if (BNIN) {
        acc.x = fmaf(acc.x, sc.x, sh.x);
        acc.y = fmaf(acc.y, sc.y, sh.y);
        acc.z = fmaf(acc.z, sc.z, sh.z);
        acc.w = fmaf(acc.w, sc.w, sh.w);
    }
    int beg = row_ptr[n], end = row_ptr[n + 1];
    for (int e = beg; e < end; ++e) {
        int src = csr_src[e];
        float4 v = *(const float4*)(x + (size_t)src * din + col);
        if (BNIN) {
            v.x = fmaf(v.x, sc.x, sh.x);
            v.y = fmaf(v.y, sc.y, sh.y);
            v.z = fmaf(v.z, sc.z, sh.z);
            v.w = fmaf(v.w, sc.w, sh.w);
        }
        acc.x += fmaxf(v.x, 0.f);
        acc.y += fmaxf(v.y, 0.f);
        acc.z += fmaxf(v.z, 0.f);
        acc.w += fmaxf(v.w, 0.f);
    }
    *(float4*)(agg + (size_t)n * fin + col) = acc;
    if (j < 8) {
        float4 v = *(const float4*)(agg_e + (size_t)n * DE + (j << 2));
        *(float4*)(agg + (size_t)n * fin + din + (j << 2)) = v;
    }
}

// ---------------------------------------------------------------------------
// fp16 fused MLP: xout = relu( relu(A@W1+b1) @ W2 + b2 ), + BN stats.
// Single-fp16 operands (10-bit mantissa; measured bf16 absmax 0.64 -> /8 ~ 0.08).
// Whole A tile (32 x K fp16) staged once in LDS; h1 reuses the same plane.
// Barrier-free K-loops; B frags pre-swizzled fp16 from L2. ~19KB LDS -> 8 blk/CU.
__global__ __launch_bounds__(256)
void fused_mlp_kernel(const float* __restrict__ A,
                      const _Float16* __restrict__ B1, const float* __restrict__ bias1,
                      const _Float16* __restrict__ B2, const float* __restrict__ bias2,
                      float* __restrict__ C, int K1, float* __restrict__ bnslot) {
    __shared__ __align__(16) _Float16 sBuf[32 * KSTR];   // A tile, then h1
    const int t = threadIdx.x;
    const int l = t & 63;
    const int w = t >> 6;
    const int lr = l & 15;
    const int lq = l >> 4;
    const int row0 = blockIdx.x << 5;   // 32 rows/block
    const int cb = w << 6;
    const int nkt1 = K1 >> 5;

    // ---- stage whole A tile (32 x K1) fp32 -> fp16 ----
    {
        const int r = t >> 3, j = t & 7;
        const int gr = row0 + r;
        const bool ok = (gr < N_NODES);
        const float* ap = A + (size_t)gr * K1 + (j << 2);
        for (int kt = 0; kt < nkt1; ++kt) {
            float4 a = {0.f, 0.f, 0.f, 0.f};
            if (ok) a = *(const float4*)(ap + (kt << 5));
            f16x4 h = {(_Float16)a.x, (_Float16)a.y, (_Float16)a.z, (_Float16)a.w};
            *(f16x4*)&sBuf[r * KSTR + (kt << 5) + (j << 2)] = h;
        }
    }
    __syncthreads();

    // ---- phase 1: A @ W1 (barrier-free) ----
    f32x4 acc1[2][4];
#pragma unroll
    for (int mt = 0; mt < 2; ++mt)
#pragma unroll
        for (int nt = 0; nt < 4; ++nt) acc1[mt][nt] = (f32x4){0.f, 0.f, 0.f, 0.f};
    for (int kt = 0; kt < nkt1; ++kt) {
        f16x8 af[2], bf[4];
#pragma unroll
        for (int mt = 0; mt < 2; ++mt)
            af[mt] = *(const f16x8*)&sBuf[(mt * 16 + lr) * KSTR + (kt << 5) + (lq << 3)];
        const size_t bb = ((size_t)(kt * 16 + (w << 2))) * 512 + (l << 3);
#pragma unroll
        for (int nt = 0; nt < 4; ++nt)
            bf[nt] = *(const f16x8*)(B1 + bb + nt * 512);
#pragma unroll
        for (int mt = 0; mt < 2; ++mt)
#pragma unroll
            for (int nt = 0; nt < 4; ++nt)
                acc1[mt][nt] = __builtin_amdgcn_mfma_f32_16x16x32_f16(
                    af[mt], bf[nt], acc1[mt][nt], 0, 0, 0);
    }
    __syncthreads();   // A tile dead; reuse plane for h1

    // ---- epilogue 1: relu(h1) -> LDS fp16 ----
#pragma unroll
    for (int nt = 0; nt < 4; ++nt) {
        int col = cb + nt * 16 + lr;
        float bv = bias1[col];
#pragma unroll
        for (int mt = 0; mt < 2; ++mt)
#pragma unroll
            for (int i = 0; i < 4; ++i) {
                int rr = mt * 16 + lq * 4 + i;
                sBuf[rr * KSTR + col] = (_Float16)fmaxf(acc1[mt][nt][i] + bv, 0.f);
            }
    }
    __syncthreads();

    // ---- phase 2: h1 @ W2 (barrier-free) ----
    f32x4 acc2[2][4];
#pragma unroll
    for (int mt = 0; mt < 2; ++mt)
#pragma unroll
        for (int nt = 0; nt < 4; ++nt) acc2[mt][nt] = (f32x4){0.f, 0.f, 0.f, 0.f};
#pragma unroll
    for (int kt = 0; kt < 8; ++kt) {
        f16x8 af[2], bf[4];
#pragma unroll
        for (int mt = 0; mt < 2; ++mt)
            af[mt] = *(const f16x8*)&sBuf[(mt * 16 + lr) * KSTR + (kt << 5) + (lq << 3)];
        const size_t bb = ((size_t)(kt * 16 + (w << 2))) * 512 + (l << 3);
#pragma unroll
        for (int nt = 0; nt < 4; ++nt)
            bf[nt] = *(const f16x8*)(B2 + bb + nt * 512);
#pragma unroll
        for (int mt = 0; mt < 2; ++mt)
#pragma unroll
            for (int nt = 0; nt < 4; ++nt)
                acc2[mt][nt] = __builtin_amdgcn_mfma_f32_16x16x32_f16(
                    af[mt], bf[nt], acc2[mt][nt], 0, 0, 0);
    }

    // ---- epilogue 2: bias + relu + store + BN stats ----
    float* slot = bnslot + (size_t)(blockIdx.x & (BN_SLOTS - 1)) * 512;
#pragma unroll
    for (int nt = 0; nt < 4; ++nt) {
        int col = cb + nt * 16 + lr;
        float bv = bias2[col];
        float s = 0.f, qq = 0.f;
#pragma unroll
        for (int mt = 0; mt < 2; ++mt)
#pragma unroll
            for (int i = 0; i < 4; ++i) {
                int row = row0 + mt * 16 + lq * 4 + i;
                if (row < N_NODES) {
                    float o = fmaxf(acc2[mt][nt][i] + bv, 0.f);
                    C[(size_t)row * 256 + col] = o;
                    s += o; qq += o * o;
                }
            }
        s += __shfl_xor(s, 16); s += __shfl_xor(s, 32);
        qq += __shfl_xor(qq, 16); qq += __shfl_xor(qq, 32);
        if (lq == 0) {
            atomicAdd(&slot[col], s);
            atomicAdd(&slot[256 + col], qq);
        }
    }
}

// reduce BN_SLOTS slots -> scale/shift
__global__ void bn_finalize_kernel(const float* __restrict__ slots,
                                   const float* __restrict__ g, const float* __restrict__ beta,
                                   float* __restrict__ scale, float* __restrict__ shift) {
    int c = threadIdx.x;
    float s = 0.f, q = 0.f;
    for (int k = 0; k < BN_SLOTS; ++k) {
        s += slots[(size_t)k * 512 + c];
        q += slots[(size_t)k * 512 + 256 + c];
    }
    float mu = s * (1.0f / N_NODES);
    float var = q * (1.0f / N_NODES) - mu * mu;
    float rstd = rsqrtf(var + 1e-5f);
    float sc = g[c] * rstd;
    scale[c] = sc;
    shift[c] = beta[c] - mu * sc;
}

// segmented sqrt-pool with BN applied at load; no atomics
__global__ __launch_bounds__(256)
void pool_seg_kernel(const float* __restrict__ h, const int* __restrict__ ptr,
                     const float* __restrict__ bnsc, const float* __restrict__ bnsh,
                     float* __restrict__ out, int nseg) {
    int t = threadIdx.x;
    int g = t >> 6;
    int j = t & 63;
    int s = blockIdx.x * 4 + g;
    if (s >= nseg) return;
    int beg = ptr[s], end = ptr[s + 1];
    int col = j << 2;
    float4 sc = *(const float4*)(bnsc + col);
    float4 sh = *(const float4*)(bnsh + col);
    float4 acc = {0.f, 0.f, 0.f, 0.f};
    for (int i = beg; i < end; ++i) {
        float4 v = *(const float4*)(h + (size_t)i * 256 + col);
        acc.x += fmaf(v.x, sc.x, sh.x);
        acc.y += fmaf(v.y, sc.y, sh.y);
        acc.z += fmaf(v.z, sc.z, sh.z);
        acc.w += fmaf(v.w, sc.w, sh.w);
    }
    float w = rsqrtf(fmaxf((float)(end - beg), 1.0f));
    float4 o = {acc.x * w, acc.y * w, acc.z * w, acc.w * w};
    *(float4*)(out + (size_t)s * 256 + col) = o;
}

// ---------------------------------------------------------------------------
extern "C" void kernel_launch(void* const* d_in, const int* in_sizes, int n_in,
                              void* d_out, int out_size, void* d_ws, size_t ws_size,
                              hipStream_t stream) {
    const float* x  = (const float*)d_in[0];
    const float* ea = (const float*)d_in[1];
    const int*   ei = (const int*)d_in[2];
    const int*   fb = (const int*)d_in[3];
    const int*   gb = (const int*)d_in[4];
    const float* W1[3]   = {(const float*)d_in[5],  (const float*)d_in[11], (const float*)d_in[17]};
    const float* B1[3]   = {(const float*)d_in[6],  (const float*)d_in[12], (const float*)d_in[18]};
    const float* W2[3]   = {(const float*)d_in[7],  (const float*)d_in[13], (const float*)d_in[19]};
    const float* B2[3]   = {(const float*)d_in[8],  (const float*)d_in[14], (const float*)d_in[20]};
    const float* G[3]    = {(const float*)d_in[9],  (const float*)d_in[15], (const float*)d_in[21]};
    const float* BETA[3] = {(const float*)d_in[10], (const float*)d_in[16], (const float*)d_in[22]};

    const int FIN[3] = {160, 288, 288};
    const int NBLK = (N_NODES + 255) / 256;      // scan blocks

    float* ws = (float*)d_ws;
    size_t off = 0;
    float* agg   = ws + off; off += (size_t)N_NODES * 288;
    float* bufA  = ws + off; off += (size_t)N_NODES * 256;
    float* bufB  = ws + off; off += (size_t)N_NODES * 256;
    float* agg_e = ws + off; off += (size_t)N_NODES * DE;
    float* bnss  = ws + off; off += 3 * 512;                 // per layer: scale|shift
    float* bnslots = ws + off; off += (size_t)3 * BN_SLOTS * 512;
    _Float16* w1f[3]; _Float16* w2f[3];
    {
        _Float16* sw = (_Float16*)(ws + off);
        _Float16* sw0 = sw;
        for (int l = 0; l < 3; ++l) { w1f[l] = sw; sw += 256 * FIN[l]; }
        for (int l = 0; l < 3; ++l) { w2f[l] = sw; sw += 256 * 256; }
        off += (size_t)(sw - sw0 + 1) / 2;
    }
    int* iw      = (int*)(ws + off);
    int* row_ptr = iw;                     iw += N_NODES + 1;
    int* deg     = iw;                     iw += N_NODES;
    int* fill    = iw;                     iw += N_NODES;
    int* csr_src = iw;                     iw += N_EDGES;
    int* csr_eid = iw;                     iw += N_EDGES;
    int* frag_ptr = iw;                    iw += N_FRAG + 1;
    int* graph_ptr = iw;                   iw += N_GRAPH + 1;
    int* bsum    = iw;                     iw += NBLK;

    hipMemsetAsync(deg, 0, 2 * N_NODES * sizeof(int), stream);
    hipMemsetAsync(bnslots, 0, (size_t)3 * BN_SLOTS * 512 * sizeof(float), stream);

    // weight fragment-swizzle to fp16 (once per layer)
    for (int l = 0; l < 3; ++l) {
        bs16_kernel<<<(FIN[l] * 256 + 255) / 256, 256, 0, stream>>>(W1[l], w1f[l], FIN[l]);
        bs16_kernel<<<(256 * 256 + 255) / 256, 256, 0, stream>>>(W2[l], w2f[l], 256);
    }

    // CSR build (hierarchical scan)
    count_deg_kernel<<<(N_EDGES + 255) / 256, 256, 0, stream>>>(ei, deg);
    block_sum_kernel<<<NBLK, 256, 0, stream>>>(deg, bsum);
    top_scan_kernel<<<1, 256, 0, stream>>>(bsum, NBLK);
    final_scan_kernel<<<NBLK, 256, 0, stream>>>(deg, bsum, row_ptr);
    fill_csr_kernel<<<(N_EDGES + 255) / 256, 256, 0, stream>>>(ei, row_ptr, fill, csr_src, csr_eid);

    segptr_kernel<<<(N_FRAG + 1 + 255) / 256, 256, 0, stream>>>(fb, N_FRAG, frag_ptr);
    segptr_kernel<<<(N_GRAPH + 1 + 255) / 256, 256, 0, stream>>>(gb, N_GRAPH, graph_ptr);

    edge_gather_kernel<<<(N_NODES + 31) / 32, 256, 0, stream>>>(ea, row_ptr, csr_eid, agg_e);

    const int nblk_mlp = (N_NODES + 31) / 32;    // 1563 blocks, 32 rows each
    const float* xin = x;
    float* outs[3] = {bufA, bufB, bufA};
    for (int l = 0; l < 3; ++l) {
        const int din = (l == 0) ? 128 : 256;
        const int fin = FIN[l];
        const int gl2 = (din == 128) ? 5 : 6;
        const int npb = 256 >> gl2;
        float* slotsL = bnslots + (size_t)l * BN_SLOTS * 512;
        float* bscale = bnss + l * 512;
        float* bshift = bscale + 256;
        const float* psc = (l > 0) ? bnss + (l - 1) * 512 : nullptr;  // prev layer BN
        const float* psh = (l > 0) ? psc + 256 : nullptr;

        if (l == 0)
            gather_agg_kernel<false><<<(N_NODES + npb - 1) / npb, 256, 0, stream>>>(
                xin, row_ptr, csr_src, agg_e, agg, nullptr, nullptr, din, fin, gl2);
        else
            gather_agg_kernel<true><<<(N_NODES + npb - 1) / npb, 256, 0, stream>>>(
                xin, row_ptr, csr_src, agg_e, agg, psc, psh, din, fin, gl2);
        fused_mlp_kernel<<<nblk_mlp, 256, 0, stream>>>(
            agg, w1f[l], B1[l], w2f[l], B2[l], outs[l], fin, slotsL);
        bn_finalize_kernel<<<1, 256, 0, stream>>>(slotsL, G[l], BETA[l], bscale, bshift);
        xin = outs[l];   // pre-BN h; BN applied by next consumer
    }

    const float* fsc = bnss + 2 * 512;   // layer-2 BN scale/shift
    const float* fsh = fsc + 256;
    pool_seg_kernel<<<(N_FRAG + 3) / 4, 256, 0, stream>>>(bufA, frag_ptr, fsc, fsh,
                                                          (float*)d_out, N_FRAG);
    pool_seg_kernel<<<(N_GRAPH + 3) / 4, 256, 0, stream>>>(bufA, graph_ptr, fsc, fsh,
                                                           (float*)d_out + (size_t)N_FRAG * 256, N_GRAPH);
}

// Round 12
// 431.653 us; speedup vs baseline: 1.3349x; 1.1100x over previous
//
#include <hip/hip_runtime.h>

#define N_NODES 50000
#define N_EDGES 200000
#define DE 32
#define N_FRAG 10000
#define N_GRAPH 2000
#define BN_SLOTS 32
#define KSTR 296   // LDS stride (fp16 elems) for the 32-row A/h1 plane

typedef _Float16 f16x8 __attribute__((ext_vector_type(8)));
typedef _Float16 f16x4 __attribute__((ext_vector_type(4)));
typedef __attribute__((ext_vector_type(4))) float f32x4;

__device__ __forceinline__ float4 ld4(const float* p) { return *(const float4*)p; }
__device__ __forceinline__ float4 ld4(const _Float16* p) {
    f16x4 h = *(const f16x4*)p;
    float4 v; v.x = (float)h[0]; v.y = (float)h[1]; v.z = (float)h[2]; v.w = (float)h[3];
    return v;
}
__device__ __forceinline__ void st4h(_Float16* p, float4 v) {
    f16x4 h = {(_Float16)v.x, (_Float16)v.y, (_Float16)v.z, (_Float16)v.w};
    *(f16x4*)p = h;
}

// ---------------------------------------------------------------------------
// CSR build: in-degree count, hierarchical scan, fill
__global__ __launch_bounds__(256)
void count_deg_kernel(const int* __restrict__ ei, int* __restrict__ deg) {
    int e = blockIdx.x * 256 + threadIdx.x;
    if (e < N_EDGES) atomicAdd(&deg[ei[N_EDGES + e]], 1);
}

__global__ __launch_bounds__(256)
void block_sum_kernel(const int* __restrict__ deg, int* __restrict__ bsum) {
    int i = blockIdx.x * 256 + threadIdx.x;
    int v = (i < N_NODES) ? deg[i] : 0;
#pragma unroll
    for (int o = 1; o < 64; o <<= 1) v += __shfl_xor(v, o);
    __shared__ int wsum[4];
    if ((threadIdx.x & 63) == 0) wsum[threadIdx.x >> 6] = v;
    __syncthreads();
    if (threadIdx.x == 0) bsum[blockIdx.x] = wsum[0] + wsum[1] + wsum[2] + wsum[3];
}

__global__ __launch_bounds__(256)
void top_scan_kernel(int* __restrict__ bsum, int nb) {
    __shared__ int s[256];
    int t = threadIdx.x;
    s[t] = (t < nb) ? bsum[t] : 0;
    __syncthreads();
    for (int o = 1; o < 256; o <<= 1) {
        int v = s[t];
        int a = (t >= o) ? s[t - o] : 0;
        __syncthreads();
        s[t] = v + a;
        __syncthreads();
    }
    if (t < nb) bsum[t] = (t > 0) ? s[t - 1] : 0;
}

__global__ __launch_bounds__(256)
void final_scan_kernel(const int* __restrict__ deg, const int* __restrict__ bsum,
                       int* __restrict__ ptr) {
    __shared__ int s[256];
    int i = blockIdx.x * 256 + threadIdx.x;
    int t = threadIdx.x;
    int v = (i < N_NODES) ? deg[i] : 0;
    s[t] = v;
    __syncthreads();
    for (int o = 1; o < 256; o <<= 1) {
        int x = s[t];
        int a = (t >= o) ? s[t - o] : 0;
        __syncthreads();
        s[t] = x + a;
        __syncthreads();
    }
    int incl = s[t];
    int base = bsum[blockIdx.x];
    if (i < N_NODES) ptr[i] = base + incl - v;
    if (i == N_NODES - 1) ptr[N_NODES] = base + incl;
}

__global__ __launch_bounds__(256)
void fill_csr_kernel(const int* __restrict__ ei, const int* __restrict__ row_ptr,
                     int* __restrict__ fill, int* __restrict__ csr_src,
                     int* __restrict__ csr_eid) {
    int e = blockIdx.x * 256 + threadIdx.x;
    if (e >= N_EDGES) return;
    int dst = ei[N_EDGES + e];
    int pos = row_ptr[dst] + atomicAdd(&fill[dst], 1);
    csr_src[pos] = ei[e];
    csr_eid[pos] = e;
}

__global__ __launch_bounds__(256)
void segptr_kernel(const int* __restrict__ batch, int nseg, int* __restrict__ ptr) {
    int s = blockIdx.x * 256 + threadIdx.x;
    if (s > nseg) return;
    int lo = 0, hi = N_NODES;
    while (lo < hi) {
        int mid = (lo + hi) >> 1;
        if (batch[mid] < s) lo = mid + 1; else hi = mid;
    }
    ptr[s] = lo;
}

// ---------------------------------------------------------------------------
// W [K][256] fp32 -> fragment-swizzled fp16 BS:
// BS[kt][cg][lane][j] = fp16(W[kt*32 + (lane>>4)*8 + j][cg*16 + (lane&15)])
__global__ __launch_bounds__(256)
void bs16_kernel(const float* __restrict__ W, _Float16* __restrict__ BS, int K) {
    int id = blockIdx.x * 256 + threadIdx.x;
    if (id >= K * 256) return;
    int j  = id & 7;
    int l  = (id >> 3) & 63;
    int cg = (id >> 9) & 15;
    int kt = id >> 13;
    int col = cg * 16 + (l & 15);
    int k   = kt * 32 + (l >> 4) * 8 + j;
    BS[id] = (_Float16)W[(size_t)k * 256 + col];
}

// ---------------------------------------------------------------------------
// agg_e[n] = sum over incoming edges of relu(edge_attr[e])  [N,32]
__global__ __launch_bounds__(256)
void edge_gather_kernel(const float* __restrict__ ea, const int* __restrict__ row_ptr,
                        const int* __restrict__ csr_eid, float* __restrict__ agg_e) {
    int t = threadIdx.x;
    int g = t >> 3;
    int j = t & 7;
    int n = blockIdx.x * 32 + g;
    if (n >= N_NODES) return;
    int col = j << 2;
    float4 acc = {0.f, 0.f, 0.f, 0.f};
    int beg = row_ptr[n], end = row_ptr[n + 1];
    for (int e = beg; e < end; ++e) {
        int eid = csr_eid[e];
        float4 v = *(const float4*)(ea + (size_t)eid * DE + col);
        acc.x += fmaxf(v.x, 0.f);
        acc.y += fmaxf(v.y, 0.f);
        acc.z += fmaxf(v.z, 0.f);
        acc.w += fmaxf(v.w, 0.f);
    }
    *(float4*)(agg_e + (size_t)n * DE + col) = acc;
}

// agg[n][0:din] = xin[n] + sum relu(xin[src]);  agg[n][din:fin] = agg_e[n]
// Output agg is fp16 (value identical to staging-time rounding in the old code).
// If BNIN: xin is pre-BN h (fp16), apply x = scale*h + shift at load.
template <bool BNIN, typename T>
__global__ __launch_bounds__(256)
void gather_agg_kernel(const T* __restrict__ x, const int* __restrict__ row_ptr,
                       const int* __restrict__ csr_src, const float* __restrict__ agg_e,
                       _Float16* __restrict__ agg, const float* __restrict__ bnsc,
                       const float* __restrict__ bnsh, int din, int fin, int gsize_log2) {
    int t = threadIdx.x;
    int g = t >> gsize_log2;
    int j = t & ((1 << gsize_log2) - 1);
    int n = blockIdx.x * (256 >> gsize_log2) + g;
    if (n >= N_NODES) return;
    int col = j << 2;
    float4 sc, sh;
    if (BNIN) {
        sc = *(const float4*)(bnsc + col);
        sh = *(const float4*)(bnsh + col);
    }
    float4 acc = ld4(x + (size_t)n * din + col);   // self term
    if (BNIN) {
        acc.x = fmaf(acc.x, sc.x, sh.x);
        acc.y = fmaf(acc.y, sc.y, sh.y);
        acc.z = fmaf(acc.z, sc.z, sh.z);
        acc.w = fmaf(acc.w, sc.w, sh.w);
    }
    int beg = row_ptr[n], end = row_ptr[n + 1];
    for (int e = beg; e < end; ++e) {
        int src = csr_src[e];
        float4 v = ld4(x + (size_t)src * din + col);
        if (BNIN) {
            v.x = fmaf(v.x, sc.x, sh.x);
            v.y = fmaf(v.y, sc.y, sh.y);
            v.z = fmaf(v.z, sc.z, sh.z);
            v.w = fmaf(v.w, sc.w, sh.w);
        }
        acc.x += fmaxf(v.x, 0.f);
        acc.y += fmaxf(v.y, 0.f);
        acc.z += fmaxf(v.z, 0.f);
        acc.w += fmaxf(v.w, 0.f);
    }
    st4h(agg + (size_t)n * fin + col, acc);
    if (j < 8) {
        float4 v = *(const float4*)(agg_e + (size_t)n * DE + (j << 2));
        st4h(agg + (size_t)n * fin + din + (j << 2), v);
    }
}

// ---------------------------------------------------------------------------
// fp16 fused MLP: xout = fp16(relu( relu(A@W1+b1) @ W2 + b2 )), + BN stats.
// A tile already fp16 -> staging is a pure copy. h1 reuses the LDS plane.
// Barrier-free K-loops; B frags pre-swizzled fp16 from L2. ~19KB LDS.
__global__ __launch_bounds__(256)
void fused_mlp_kernel(const _Float16* __restrict__ A,
                      const _Float16* __restrict__ B1, const float* __restrict__ bias1,
                      const _Float16* __restrict__ B2, const float* __restrict__ bias2,
                      _Float16* __restrict__ C, int K1, float* __restrict__ bnslot) {
    __shared__ __align__(16) _Float16 sBuf[32 * KSTR];   // A tile, then h1
    const int t = threadIdx.x;
    const int l = t & 63;
    const int w = t >> 6;
    const int lr = l & 15;
    const int lq = l >> 4;
    const int row0 = blockIdx.x << 5;   // 32 rows/block
    const int cb = w << 6;
    const int nkt1 = K1 >> 5;

    // ---- stage whole A tile (32 x K1 fp16, pure copy) ----
    {
        const int r = t >> 3, j = t & 7;
        const int gr = row0 + r;
        const bool ok = (gr < N_NODES);
        const _Float16* ap = A + (size_t)gr * K1 + (j << 2);
        for (int kt = 0; kt < nkt1; ++kt) {
            f16x4 a = {0, 0, 0, 0};
            if (ok) a = *(const f16x4*)(ap + (kt << 5));
            *(f16x4*)&sBuf[r * KSTR + (kt << 5) + (j << 2)] = a;
        }
    }
    __syncthreads();

    // ---- phase 1: A @ W1 (barrier-free) ----
    f32x4 acc1[2][4];
#pragma unroll
    for (int mt = 0; mt < 2; ++mt)
#pragma unroll
        for (int nt = 0; nt < 4; ++nt) acc1[mt][nt] = (f32x4){0.f, 0.f, 0.f, 0.f};
    for (int kt = 0; kt < nkt1; ++kt) {
        f16x8 af[2], bf[4];
#pragma unroll
        for (int mt = 0; mt < 2; ++mt)
            af[mt] = *(const f16x8*)&sBuf[(mt * 16 + lr) * KSTR + (kt << 5) + (lq << 3)];
        const size_t bb = ((size_t)(kt * 16 + (w << 2))) * 512 + (l << 3);
#pragma unroll
        for (int nt = 0; nt < 4; ++nt)
            bf[nt] = *(const f16x8*)(B1 + bb + nt * 512);
#pragma unroll
        for (int mt = 0; mt < 2; ++mt)
#pragma unroll
            for (int nt = 0; nt < 4; ++nt)
                acc1[mt][nt] = __builtin_amdgcn_mfma_f32_16x16x32_f16(
                    af[mt], bf[nt], acc1[mt][nt], 0, 0, 0);
    }
    __syncthreads();   // A tile dead; reuse plane for h1

    // ---- epilogue 1: relu(h1) -> LDS fp16 ----
#pragma unroll
    for (int nt = 0; nt < 4; ++nt) {
        int col = cb + nt * 16 + lr;
        float bv = bias1[col];
#pragma unroll
        for (int mt = 0; mt < 2; ++mt)
#pragma unroll
            for (int i = 0; i < 4; ++i) {
                int rr = mt * 16 + lq * 4 + i;
                sBuf[rr * KSTR + col] = (_Float16)fmaxf(acc1[mt][nt][i] + bv, 0.f);
            }
    }
    __syncthreads();

    // ---- phase 2: h1 @ W2 (barrier-free) ----
    f32x4 acc2[2][4];
#pragma unroll
    for (int mt = 0; mt < 2; ++mt)
#pragma unroll
        for (int nt = 0; nt < 4; ++nt) acc2[mt][nt] = (f32x4){0.f, 0.f, 0.f, 0.f};
#pragma unroll
    for (int kt = 0; kt < 8; ++kt) {
        f16x8 af[2], bf[4];
#pragma unroll
        for (int mt = 0; mt < 2; ++mt)
            af[mt] = *(const f16x8*)&sBuf[(mt * 16 + lr) * KSTR + (kt << 5) + (lq << 3)];
        const size_t bb = ((size_t)(kt * 16 + (w << 2))) * 512 + (l << 3);
#pragma unroll
        for (int nt = 0; nt < 4; ++nt)
            bf[nt] = *(const f16x8*)(B2 + bb + nt * 512);
#pragma unroll
        for (int mt = 0; mt < 2; ++mt)
#pragma unroll
            for (int nt = 0; nt < 4; ++nt)
                acc2[mt][nt] = __builtin_amdgcn_mfma_f32_16x16x32_f16(
                    af[mt], bf[nt], acc2[mt][nt], 0, 0, 0);
    }

    // ---- epilogue 2: bias + relu + fp16 store + BN stats ----
    float* slot = bnslot + (size_t)(blockIdx.x & (BN_SLOTS - 1)) * 512;
#pragma unroll
    for (int nt = 0; nt < 4; ++nt) {
        int col = cb + nt * 16 + lr;
        float bv = bias2[col];
        float s = 0.f, qq = 0.f;
#pragma unroll
        for (int mt = 0; mt < 2; ++mt)
#pragma unroll
            for (int i = 0; i < 4; ++i) {
                int row = row0 + mt * 16 + lq * 4 + i;
                if (row < N_NODES) {
                    float o = fmaxf(acc2[mt][nt][i] + bv, 0.f);
                    C[(size_t)row * 256 + col] = (_Float16)o;
                    s += o; qq += o * o;
                }
            }
        s += __shfl_xor(s, 16); s += __shfl_xor(s, 32);
        qq += __shfl_xor(qq, 16); qq += __shfl_xor(qq, 32);
        if (lq == 0) {
            atomicAdd(&slot[col], s);
            atomicAdd(&slot[256 + col], qq);
        }
    }
}

// reduce BN_SLOTS slots -> scale/shift
__global__ void bn_finalize_kernel(const float* __restrict__ slots,
                                   const float* __restrict__ g, const float* __restrict__ beta,
                                   float* __restrict__ scale, float* __restrict__ shift) {
    int c = threadIdx.x;
    float s = 0.f, q = 0.f;
    for (int k = 0; k < BN_SLOTS; ++k) {
        s += slots[(size_t)k * 512 + c];
        q += slots[(size_t)k * 512 + 256 + c];
    }
    float mu = s * (1.0f / N_NODES);
    float var = q * (1.0f / N_NODES) - mu * mu;
    float rstd = rsqrtf(var + 1e-5f);
    float sc = g[c] * rstd;
    scale[c] = sc;
    shift[c] = beta[c] - mu * sc;
}

// segmented sqrt-pool (fp16 input) with BN applied at load; fp32 output
__global__ __launch_bounds__(256)
void pool_seg_kernel(const _Float16* __restrict__ h, const int* __restrict__ ptr,
                     const float* __restrict__ bnsc, const float* __restrict__ bnsh,
                     float* __restrict__ out, int nseg) {
    int t = threadIdx.x;
    int g = t >> 6;
    int j = t & 63;
    int s = blockIdx.x * 4 + g;
    if (s >= nseg) return;
    int beg = ptr[s], end = ptr[s + 1];
    int col = j << 2;
    float4 sc = *(const float4*)(bnsc + col);
    float4 sh = *(const float4*)(bnsh + col);
    float4 acc = {0.f, 0.f, 0.f, 0.f};
    for (int i = beg; i < end; ++i) {
        float4 v = ld4(h + (size_t)i * 256 + col);
        acc.x += fmaf(v.x, sc.x, sh.x);
        acc.y += fmaf(v.y, sc.y, sh.y);
        acc.z += fmaf(v.z, sc.z, sh.z);
        acc.w += fmaf(v.w, sc.w, sh.w);
    }
    float w = rsqrtf(fmaxf((float)(end - beg), 1.0f));
    float4 o = {acc.x * w, acc.y * w, acc.z * w, acc.w * w};
    *(float4*)(out + (size_t)s * 256 + col) = o;
}

// ---------------------------------------------------------------------------
extern "C" void kernel_launch(void* const* d_in, const int* in_sizes, int n_in,
                              void* d_out, int out_size, void* d_ws, size_t ws_size,
                              hipStream_t stream) {
    const float* x  = (const float*)d_in[0];
    const float* ea = (const float*)d_in[1];
    const int*   ei = (const int*)d_in[2];
    const int*   fb = (const int*)d_in[3];
    const int*   gb = (const int*)d_in[4];
    const float* W1[3]   = {(const float*)d_in[5],  (const float*)d_in[11], (const float*)d_in[17]};
    const float* B1[3]   = {(const float*)d_in[6],  (const float*)d_in[12], (const float*)d_in[18]};
    const float* W2[3]   = {(const float*)d_in[7],  (const float*)d_in[13], (const float*)d_in[19]};
    const float* B2[3]   = {(const float*)d_in[8],  (const float*)d_in[14], (const float*)d_in[20]};
    const float* G[3]    = {(const float*)d_in[9],  (const float*)d_in[15], (const float*)d_in[21]};
    const float* BETA[3] = {(const float*)d_in[10], (const float*)d_in[16], (const float*)d_in[22]};

    const int FIN[3] = {160, 288, 288};
    const int NBLK = (N_NODES + 255) / 256;      // scan blocks

    float* ws = (float*)d_ws;
    size_t off = 0;
    _Float16* agg  = (_Float16*)(ws + off); off += (size_t)N_NODES * 144;  // N x 288 fp16
    _Float16* bufA = (_Float16*)(ws + off); off += (size_t)N_NODES * 128;  // N x 256 fp16
    _Float16* bufB = (_Float16*)(ws + off); off += (size_t)N_NODES * 128;
    float* agg_e = ws + off; off += (size_t)N_NODES * DE;
    float* bnss  = ws + off; off += 3 * 512;                 // per layer: scale|shift
    float* bnslots = ws + off; off += (size_t)3 * BN_SLOTS * 512;
    _Float16* w1f[3]; _Float16* w2f[3];
    {
        _Float16* sw = (_Float16*)(ws + off);
        _Float16* sw0 = sw;
        for (int l = 0; l < 3; ++l) { w1f[l] = sw; sw += 256 * FIN[l]; }
        for (int l = 0; l < 3; ++l) { w2f[l] = sw; sw += 256 * 256; }
        off += (size_t)(sw - sw0 + 1) / 2;
    }
    int* iw      = (int*)(ws + off);
    int* row_ptr = iw;                     iw += N_NODES + 1;
    int* deg     = iw;                     iw += N_NODES;
    int* fill    = iw;                     iw += N_NODES;
    int* csr_src = iw;                     iw += N_EDGES;
    int* csr_eid = iw;                     iw += N_EDGES;
    int* frag_ptr = iw;                    iw += N_FRAG + 1;
    int* graph_ptr = iw;                   iw += N_GRAPH + 1;
    int* bsum    = iw;                     iw += NBLK;

    hipMemsetAsync(deg, 0, 2 * N_NODES * sizeof(int), stream);
    hipMemsetAsync(bnslots, 0, (size_t)3 * BN_SLOTS * 512 * sizeof(float), stream);

    // weight fragment-swizzle to fp16 (once per layer)
    for (int l = 0; l < 3; ++l) {
        bs16_kernel<<<(FIN[l] * 256 + 255) / 256, 256, 0, stream>>>(W1[l], w1f[l], FIN[l]);
        bs16_kernel<<<(256 * 256 + 255) / 256, 256, 0, stream>>>(W2[l], w2f[l], 256);
    }

    // CSR build (hierarchical scan)
    count_deg_kernel<<<(N_EDGES + 255) / 256, 256, 0, stream>>>(ei, deg);
    block_sum_kernel<<<NBLK, 256, 0, stream>>>(deg, bsum);
    top_scan_kernel<<<1, 256, 0, stream>>>(bsum, NBLK);
    final_scan_kernel<<<NBLK, 256, 0, stream>>>(deg, bsum, row_ptr);
    fill_csr_kernel<<<(N_EDGES + 255) / 256, 256, 0, stream>>>(ei, row_ptr, fill, csr_src, csr_eid);

    segptr_kernel<<<(N_FRAG + 1 + 255) / 256, 256, 0, stream>>>(fb, N_FRAG, frag_ptr);
    segptr_kernel<<<(N_GRAPH + 1 + 255) / 256, 256, 0, stream>>>(gb, N_GRAPH, graph_ptr);

    edge_gather_kernel<<<(N_NODES + 31) / 32, 256, 0, stream>>>(ea, row_ptr, csr_eid, agg_e);

    const int nblk_mlp = (N_NODES + 31) / 32;    // 1563 blocks, 32 rows each
    _Float16* outs[3] = {bufA, bufB, bufA};
    for (int l = 0; l < 3; ++l) {
        const int din = (l == 0) ? 128 : 256;
        const int fin = FIN[l];
        const int gl2 = (din == 128) ? 5 : 6;
        const int npb = 256 >> gl2;
        float* slotsL = bnslots + (size_t)l * BN_SLOTS * 512;
        float* bscale = bnss + l * 512;
        float* bshift = bscale + 256;
        const float* psc = (l > 0) ? bnss + (l - 1) * 512 : nullptr;  // prev layer BN
        const float* psh = (l > 0) ? psc + 256 : nullptr;

        if (l == 0)
            gather_agg_kernel<false, float><<<(N_NODES + npb - 1) / npb, 256, 0, stream>>>(
                x, row_ptr, csr_src, agg_e, agg, nullptr, nullptr, din, fin, gl2);
        else
            gather_agg_kernel<true, _Float16><<<(N_NODES + npb - 1) / npb, 256, 0, stream>>>(
                outs[l - 1], row_ptr, csr_src, agg_e, agg, psc, psh, din, fin, gl2);
        fused_mlp_kernel<<<nblk_mlp, 256, 0, stream>>>(
            agg, w1f[l], B1[l], w2f[l], B2[l], outs[l], fin, slotsL);
        bn_finalize_kernel<<<1, 256, 0, stream>>>(slotsL, G[l], BETA[l], bscale, bshift);
    }

    const float* fsc = bnss + 2 * 512;   // layer-2 BN scale/shift
    const float* fsh = fsc + 256;
    pool_seg_kernel<<<(N_FRAG + 3) / 4, 256, 0, stream>>>(bufA, frag_ptr, fsc, fsh,
                                                          (float*)d_out, N_FRAG);
    pool_seg_kernel<<<(N_GRAPH + 3) / 4, 256, 0, stream>>>(bufA, graph_ptr, fsc, fsh,
                                                           (float*)d_out + (size_t)N_FRAG * 256, N_GRAPH);
}